// Round 13
// baseline (425.255 us; speedup 1.0000x reference)
//
#include <hip/hip_runtime.h>
#include <hip/hip_bf16.h>
#include <math.h>

#define DIV_UP(a,b) (((a)+(b)-1)/(b))

typedef __attribute__((ext_vector_type(8))) short short8v;
typedef __attribute__((ext_vector_type(4))) float f32x4;

__device__ __forceinline__ float bf_lo(unsigned u){ union{unsigned x; float f;} v; v.x = u << 16; return v.f; }
__device__ __forceinline__ float bf_hi(unsigned u){ union{unsigned x; float f;} v; v.x = u & 0xffff0000u; return v.f; }
__device__ __forceinline__ unsigned short f2bf(float f){
  union{float f; unsigned u;} v; v.f = f;
  unsigned r = v.u + 0x7fff + ((v.u >> 16) & 1);   // round-nearest-even
  return (unsigned short)(r >> 16);
}
__device__ __forceinline__ unsigned packbf(float a, float b){
  return (unsigned)f2bf(a) | ((unsigned)f2bf(b) << 16);
}
__device__ __forceinline__ float lrelu(float x){ return x > 0.f ? x : 0.2f*x; }

// ---------------- CSR scan ----------------
__global__ __launch_bounds__(256) void k_scan1(const int* __restrict__ deg,
                                               int* __restrict__ blocksum, int N){
  int b = blockIdx.x;
  int base = b*1024 + threadIdx.x*4;
  int s = 0;
  if (base + 3 < N){
    int4 v = *(const int4*)&deg[base];
    s = v.x + v.y + v.z + v.w;
  } else {
    for (int i = 0; i < 4; i++){ int idx = base + i; if (idx < N) s += deg[idx]; }
  }
  #pragma unroll
  for (int o = 32; o; o >>= 1) s += __shfl_down(s, o);
  __shared__ int ws[4];
  int wid = threadIdx.x >> 6, lane = threadIdx.x & 63;
  if (lane == 0) ws[wid] = s;
  __syncthreads();
  if (threadIdx.x == 0) blocksum[b] = ws[0] + ws[1] + ws[2] + ws[3];
}

// scan3: computes own block offset from raw blocksums (nb small), then local scan.
__global__ __launch_bounds__(256) void k_scan3(const int* __restrict__ deg,
                                               const int* __restrict__ blocksum, int nb,
                                               int* __restrict__ row_start,
                                               int* __restrict__ cursor, int N){
  int b = blockIdx.x;
  __shared__ int s_boff;
  if (threadIdx.x < 64){
    int acc = 0;
    for (int base = 0; base < nb; base += 64){
      int idx = base + threadIdx.x;
      if (idx < nb && idx < b) acc += blocksum[idx];
    }
    #pragma unroll
    for (int o = 32; o; o >>= 1) acc += __shfl_down(acc, o);
    if (threadIdx.x == 0) s_boff = acc;
  }
  int base = b*1024 + threadIdx.x*4;
  int v[4];
  #pragma unroll
  for (int i = 0; i < 4; i++){ int idx = base + i; v[i] = (idx < N) ? deg[idx] : 0; }
  int s = v[0] + v[1] + v[2] + v[3];
  int lane = threadIdx.x & 63, wid = threadIdx.x >> 6;
  int inc = s;
  #pragma unroll
  for (int o = 1; o < 64; o <<= 1){ int t = __shfl_up(inc, o); if (lane >= o) inc += t; }
  __shared__ int wsum[4];
  if (lane == 63) wsum[wid] = inc;
  __syncthreads();
  int woff = 0;
  #pragma unroll
  for (int i = 0; i < 4; i++) if (i < wid) woff += wsum[i];
  int run = s_boff + woff + inc - s;
  #pragma unroll
  for (int i = 0; i < 4; i++){
    int idx = base + i;
    if (idx < N){ row_start[idx] = run; cursor[idx] = run; run += v[i]; }
  }
  if (base < N && base + 4 >= N) row_start[N] = run;
}

// fill + layer-1 edge weights fused; weights stored TRANSPOSED w4T[h][E].
__global__ void k_fillw4(const int* __restrict__ dst, const int* __restrict__ src,
                         int* __restrict__ cursor, int* __restrict__ srcp,
                         const float4* __restrict__ el4, const float4* __restrict__ er4,
                         float* __restrict__ w4T, int E){
  int i = blockIdx.x*blockDim.x + threadIdx.x;
  if (i < E){
    int d = dst[i], s = src[i];
    int p = atomicAdd(&cursor[d], 1);
    srcp[p] = s;
    float4 l = el4[s], r = er4[d];
    w4T[0*E + p] = __expf(lrelu(l.x + r.x));
    w4T[1*E + p] = __expf(lrelu(l.y + r.y));
    w4T[2*E + p] = __expf(lrelu(l.z + r.z));
    w4T[3*E + p] = __expf(lrelu(l.w + r.w));
  }
}

// ---------------- GEMM1 (A staged once, 4-head loop) fused with degree count ----------------
__global__ __launch_bounds__(256) void k_gemm1_count(const float* __restrict__ A, // emb [M][128]
      const float* __restrict__ B,      // W1 [128][256]
      unsigned short* __restrict__ Cbf, // feat1b [M][256]
      const float* __restrict__ al, const float* __restrict__ ar,   // [256]
      float* __restrict__ el, float* __restrict__ er, int M,        // [M][4]
      const int* __restrict__ dst, int* __restrict__ deg, int E, int gemmBlocks){
  __shared__ alignas(16) __hip_bfloat16 At[64][136];
  __shared__ alignas(16) __hip_bfloat16 Bt[64][136];
  __shared__ float elp[2][64], erp[2][64];

  if (blockIdx.x >= gemmBlocks){
    int i = (blockIdx.x - gemmBlocks)*256 + threadIdx.x;
    if (i < E) atomicAdd(&deg[dst[i]], 1);
    return;
  }

  const int tid = threadIdx.x;
  const int lane = tid & 63, w = tid >> 6;
  const int mw = w >> 1, nw = w & 1;
  const int m0 = blockIdx.x * 64;
  const int rbase = mw*32, cbase = nw*32;
  const int fr = lane & 15, fg = lane >> 4;

  #pragma unroll
  for (int i = 0; i < 8; i++){
    int q = tid + i*256;
    int row = q >> 5, c4 = q & 31;
    float4 a = make_float4(0.f,0.f,0.f,0.f);
    if (m0 + row < M) a = *(const float4*)&A[(size_t)(m0+row)*128 + c4*4];
    *(uint2*)&At[row][c4*4] = make_uint2(packbf(a.x,a.y), packbf(a.z,a.w));
  }

  for (int by = 0; by < 4; by++){
    int n0 = by * 64;
    __syncthreads();
    #pragma unroll
    for (int i = 0; i < 8; i++){
      int q = tid + i*256;
      int c = q & 63, k4 = q >> 6;
      float b0 = B[(size_t)(k4*4+0)*256 + n0 + c];
      float b1 = B[(size_t)(k4*4+1)*256 + n0 + c];
      float b2 = B[(size_t)(k4*4+2)*256 + n0 + c];
      float b3 = B[(size_t)(k4*4+3)*256 + n0 + c];
      *(uint2*)&Bt[c][k4*4] = make_uint2(packbf(b0,b1), packbf(b2,b3));
    }
    __syncthreads();

    f32x4 acc[2][2];
    #pragma unroll
    for (int i = 0; i < 2; i++)
      #pragma unroll
      for (int jj = 0; jj < 2; jj++)
        #pragma unroll
        for (int r = 0; r < 4; r++) acc[i][jj][r] = 0.f;

    #pragma unroll
    for (int ks = 0; ks < 4; ks++){
      short8v a0 = *(const short8v*)&At[rbase + fr     ][ks*32 + fg*8];
      short8v a1 = *(const short8v*)&At[rbase + 16 + fr][ks*32 + fg*8];
      short8v b0 = *(const short8v*)&Bt[cbase + fr     ][ks*32 + fg*8];
      short8v b1 = *(const short8v*)&Bt[cbase + 16 + fr][ks*32 + fg*8];
      acc[0][0] = __builtin_amdgcn_mfma_f32_16x16x32_bf16(a0, b0, acc[0][0], 0,0,0);
      acc[0][1] = __builtin_amdgcn_mfma_f32_16x16x32_bf16(a0, b1, acc[0][1], 0,0,0);
      acc[1][0] = __builtin_amdgcn_mfma_f32_16x16x32_bf16(a1, b0, acc[1][0], 0,0,0);
      acc[1][1] = __builtin_amdgcn_mfma_f32_16x16x32_bf16(a1, b1, acc[1][1], 0,0,0);
    }

    float alv[2], arv[2];
    #pragma unroll
    for (int nt = 0; nt < 2; nt++){
      int col = cbase + nt*16 + fr;
      alv[nt] = al[n0 + col];
      arv[nt] = ar[n0 + col];
    }
    #pragma unroll
    for (int mt = 0; mt < 2; mt++){
      #pragma unroll
      for (int r = 0; r < 4; r++){
        float pl = acc[mt][0][r]*alv[0] + acc[mt][1][r]*alv[1];
        float pr = acc[mt][0][r]*arv[0] + acc[mt][1][r]*arv[1];
        #pragma unroll
        for (int o = 1; o < 16; o <<= 1){ pl += __shfl_xor(pl, o); pr += __shfl_xor(pr, o); }
        if (fr == 0){
          int rl = rbase + mt*16 + fg*4 + r;
          elp[nw][rl] = pl; erp[nw][rl] = pr;
        }
      }
    }
    #pragma unroll
    for (int mt = 0; mt < 2; mt++){
      #pragma unroll
      for (int r = 0; r < 4; r++){
        int row = m0 + rbase + mt*16 + fg*4 + r;
        if (row < M){
          #pragma unroll
          for (int nt = 0; nt < 2; nt++)
            Cbf[(size_t)row*256 + n0 + cbase + nt*16 + fr] = f2bf(acc[mt][nt][r]);
        }
      }
    }
    __syncthreads();
    if (tid < 64){
      int row = m0 + tid;
      if (row < M){
        el[(size_t)row*4 + by] = elp[0][tid] + elp[1][tid];
        er[(size_t)row*4 + by] = erp[0][tid] + erp[1][tid];
      }
    }
  }
}

// ---------------- GEMM2 (layer 2), 64x64, full-K LDS, fused el/er ----------------
template<int K, int H, bool ABF>
__global__ __launch_bounds__(256) void k_gemm_mfma(const void* __restrict__ Av,
      const float* __restrict__ B, int ldb,
      unsigned short* __restrict__ Cbf,
      const float* __restrict__ al, const float* __restrict__ ar,
      float* __restrict__ el, float* __restrict__ er, int M){
  constexpr int KP = K + 8;
  __shared__ alignas(16) __hip_bfloat16 At[64][KP];
  __shared__ alignas(16) __hip_bfloat16 Bt[64][KP];
  __shared__ float elp[2][64], erp[2][64];
  const int tid = threadIdx.x;
  const int lane = tid & 63, w = tid >> 6;
  const int mw = w >> 1, nw = w & 1;
  const int m0 = blockIdx.x * 64, by = blockIdx.y, n0 = by * 64;

  if constexpr (!ABF){
    const float* A = (const float*)Av;
    #pragma unroll
    for (int i = 0; i < K/16; i++){
      int q = tid + i*256;
      int row = q / (K/4), c4 = q % (K/4);
      float4 a = make_float4(0.f,0.f,0.f,0.f);
      if (m0 + row < M) a = *(const float4*)&A[(size_t)(m0+row)*K + c4*4];
      *(uint2*)&At[row][c4*4] = make_uint2(packbf(a.x,a.y), packbf(a.z,a.w));
    }
  } else {
    const __hip_bfloat16* A = (const __hip_bfloat16*)Av;
    #pragma unroll
    for (int i = 0; i < K/32; i++){
      int q = tid + i*256;
      int row = q / (K/8), c8 = q % (K/8);
      uint4 u = make_uint4(0,0,0,0);
      if (m0 + row < M) u = *(const uint4*)&A[(size_t)(m0+row)*K + c8*8];
      *(uint4*)&At[row][c8*8] = u;
    }
  }
  #pragma unroll
  for (int i = 0; i < K/16; i++){
    int q = tid + i*256;
    int c = q & 63, k4 = q >> 6;
    float b0 = B[(size_t)(k4*4+0)*ldb + n0 + c];
    float b1 = B[(size_t)(k4*4+1)*ldb + n0 + c];
    float b2 = B[(size_t)(k4*4+2)*ldb + n0 + c];
    float b3 = B[(size_t)(k4*4+3)*ldb + n0 + c];
    *(uint2*)&Bt[c][k4*4] = make_uint2(packbf(b0,b1), packbf(b2,b3));
  }
  __syncthreads();

  f32x4 acc[2][2];
  #pragma unroll
  for (int i = 0; i < 2; i++)
    #pragma unroll
    for (int j = 0; j < 2; j++)
      #pragma unroll
      for (int r = 0; r < 4; r++) acc[i][j][r] = 0.f;

  const int rbase = mw*32, cbase = nw*32;
  const int fr = lane & 15, fg = lane >> 4;
  #pragma unroll
  for (int ks = 0; ks < K/32; ks++){
    short8v a0 = *(const short8v*)&At[rbase + fr     ][ks*32 + fg*8];
    short8v a1 = *(const short8v*)&At[rbase + 16 + fr][ks*32 + fg*8];
    short8v b0 = *(const short8v*)&Bt[cbase + fr     ][ks*32 + fg*8];
    short8v b1 = *(const short8v*)&Bt[cbase + 16 + fr][ks*32 + fg*8];
    acc[0][0] = __builtin_amdgcn_mfma_f32_16x16x32_bf16(a0, b0, acc[0][0], 0,0,0);
    acc[0][1] = __builtin_amdgcn_mfma_f32_16x16x32_bf16(a0, b1, acc[0][1], 0,0,0);
    acc[1][0] = __builtin_amdgcn_mfma_f32_16x16x32_bf16(a1, b0, acc[1][0], 0,0,0);
    acc[1][1] = __builtin_amdgcn_mfma_f32_16x16x32_bf16(a1, b1, acc[1][1], 0,0,0);
  }

  float alv[2], arv[2];
  #pragma unroll
  for (int nt = 0; nt < 2; nt++){
    int col = cbase + nt*16 + fr;
    alv[nt] = al[by*64 + col];
    arv[nt] = ar[by*64 + col];
  }
  #pragma unroll
  for (int mt = 0; mt < 2; mt++){
    #pragma unroll
    for (int r = 0; r < 4; r++){
      float pl = acc[mt][0][r]*alv[0] + acc[mt][1][r]*alv[1];
      float pr = acc[mt][0][r]*arv[0] + acc[mt][1][r]*arv[1];
      #pragma unroll
      for (int o = 1; o < 16; o <<= 1){ pl += __shfl_xor(pl, o); pr += __shfl_xor(pr, o); }
      if (fr == 0){
        int rl = rbase + mt*16 + fg*4 + r;
        elp[nw][rl] = pl; erp[nw][rl] = pr;
      }
    }
  }
  const int NN = H*64;
  #pragma unroll
  for (int mt = 0; mt < 2; mt++){
    #pragma unroll
    for (int r = 0; r < 4; r++){
      int row = m0 + rbase + mt*16 + fg*4 + r;
      if (row < M){
        #pragma unroll
        for (int nt = 0; nt < 2; nt++)
          Cbf[(size_t)row*NN + n0 + cbase + nt*16 + fr] = f2bf(acc[mt][nt][r]);
      }
    }
  }
  __syncthreads();
  if (tid < 64){
    int row = m0 + tid;
    if (row < M){
      el[(size_t)row*H + by] = elp[0][tid] + elp[1][tid];
      er[(size_t)row*H + by] = erp[0][tid] + erp[1][tid];
    }
  }
}

// ---------------- gather-aggregate H=4, COLUMN-SLICED (8 slices -> per-XCD L2) ----------------
// slice c = blockIdx&7: dims [c*32, c*32+32) of all rows (3.2 MB line set / slice).
// Wave per node; 16 edges/iter; lane -> (edge = lane>>2, subcol s = lane&3), 16B per lane.
__global__ __launch_bounds__(256) void k_gath4s(const uint4* __restrict__ fbase, // bf16 [N][256] = uint4[N*32]
      const float* __restrict__ w4T, const int* __restrict__ row_start,
      const int* __restrict__ srcp, const float* __restrict__ bias,
      __hip_bfloat16* __restrict__ outb, int N, int E, int nwaves){
  int wv = threadIdx.x >> 6, lane = threadIdx.x & 63;
  int c = blockIdx.x & 7;
  int h = c >> 1;
  int el_ = lane >> 2, s = lane & 3;
  const float* wplane = w4T + (size_t)h*E;
  const unsigned cbase = (unsigned)(c << 2);   // uint4 offset of slice in row

  int n = (blockIdx.x >> 3)*4 + wv;
  if (n >= N) return;
  int rs = row_start[n], re = row_start[n+1];

  while (true){
    int deg = re - rs;
    int nn = n + nwaves;
    int rs_n = 0, re_n = 0;
    if (nn < N){ rs_n = row_start[nn]; re_n = row_start[nn+1]; }

    float acc[8];
    #pragma unroll
    for (int k = 0; k < 8; k++) acc[k] = 0.f;
    float Sacc = 0.f;

    int i = 0;
    int full = deg & ~15;
    for (; i < full; i += 16){          // unguarded 16-edge groups
      unsigned ee = (unsigned)(rs + i + el_);
      int sb = srcp[ee];
      float w = wplane[ee];
      uint4 u = fbase[((unsigned)sb << 5) + cbase + s];
      Sacc += w;
      acc[0] += bf_lo(u.x)*w; acc[1] += bf_hi(u.x)*w;
      acc[2] += bf_lo(u.y)*w; acc[3] += bf_hi(u.y)*w;
      acc[4] += bf_lo(u.z)*w; acc[5] += bf_hi(u.z)*w;
      acc[6] += bf_lo(u.w)*w; acc[7] += bf_hi(u.w)*w;
    }
    if (i < deg){                       // guarded tail
      int e = i + el_;
      float w = 0.f; uint4 u = make_uint4(0,0,0,0);
      if (e < deg){
        unsigned ee = (unsigned)(rs + e);
        int sb = srcp[ee];
        w = wplane[ee];
        u = fbase[((unsigned)sb << 5) + cbase + s];
      }
      Sacc += w;
      acc[0] += bf_lo(u.x)*w; acc[1] += bf_hi(u.x)*w;
      acc[2] += bf_lo(u.y)*w; acc[3] += bf_hi(u.y)*w;
      acc[4] += bf_lo(u.z)*w; acc[5] += bf_hi(u.z)*w;
      acc[6] += bf_lo(u.w)*w; acc[7] += bf_hi(u.w)*w;
    }

    // reduce across the 16 edge-lanes (bits 2..5), keep s fixed
    #pragma unroll
    for (int o = 4; o < 64; o <<= 1){
      #pragma unroll
      for (int k = 0; k < 8; k++) acc[k] += __shfl_xor(acc[k], o);
      Sacc += __shfl_xor(Sacc, o);
    }

    if (el_ == 0){                      // lanes 0..3 write 8 dims each
      float inv = (deg > 0 && Sacc > 0.f) ? 1.f / Sacc : 0.f;
      int d0 = c*32 + s*8;
      float4 b0 = *(const float4*)&bias[d0];
      float4 b1 = *(const float4*)&bias[d0 + 4];
      float v0 = fmaxf(acc[0]*inv + b0.x, 0.f);
      float v1 = fmaxf(acc[1]*inv + b0.y, 0.f);
      float v2 = fmaxf(acc[2]*inv + b0.z, 0.f);
      float v3 = fmaxf(acc[3]*inv + b0.w, 0.f);
      float v4 = fmaxf(acc[4]*inv + b1.x, 0.f);
      float v5 = fmaxf(acc[5]*inv + b1.y, 0.f);
      float v6 = fmaxf(acc[6]*inv + b1.z, 0.f);
      float v7 = fmaxf(acc[7]*inv + b1.w, 0.f);
      uint4 o;
      o.x = packbf(v0, v1); o.y = packbf(v2, v3);
      o.z = packbf(v4, v5); o.w = packbf(v6, v7);
      ((uint4*)outb)[(size_t)n*32 + cbase + s] = o;
    }

    if (nn >= N) break;
    n = nn; rs = rs_n; re = re_n;
  }
}

// ---------------- gather-aggregate H=1, COLUMN-SLICED (4 slices), inline weights ----------------
// slice c = blockIdx&3: dims [c*16, c*16+16). 32 edges/iter; lane -> (edge = lane>>1, s = lane&1).
__global__ __launch_bounds__(256) void k_gath1s(const uint4* __restrict__ fbase, // bf16 [N][64] = uint4[N*8]
      const float* __restrict__ el2, const float* __restrict__ er2,
      const int* __restrict__ row_start, const int* __restrict__ srcp,
      const float* __restrict__ bias, float* __restrict__ out, int N, int nwaves){
  int wv = threadIdx.x >> 6, lane = threadIdx.x & 63;
  int c = blockIdx.x & 3;
  int el_ = lane >> 1, s = lane & 1;
  const unsigned cbase = (unsigned)(c << 1);   // uint4 offset of slice in row

  int n = (blockIdx.x >> 2)*4 + wv;
  if (n >= N) return;
  int rs = row_start[n], re = row_start[n+1];

  while (true){
    int deg = re - rs;
    int nn = n + nwaves;
    int rs_n = 0, re_n = 0;
    if (nn < N){ rs_n = row_start[nn]; re_n = row_start[nn+1]; }

    float ern = er2[n];
    float acc[8];
    #pragma unroll
    for (int k = 0; k < 8; k++) acc[k] = 0.f;
    float Sacc = 0.f;

    int i = 0;
    int full = deg & ~31;
    for (; i < full; i += 32){
      unsigned ee = (unsigned)(rs + i + el_);
      int sb = srcp[ee];
      float x = el2[sb] + ern;
      x = x > 0.f ? x : 0.2f*x;
      float w = __expf(x);
      uint4 u = fbase[((unsigned)sb << 3) + cbase + s];
      Sacc += w;
      acc[0] += bf_lo(u.x)*w; acc[1] += bf_hi(u.x)*w;
      acc[2] += bf_lo(u.y)*w; acc[3] += bf_hi(u.y)*w;
      acc[4] += bf_lo(u.z)*w; acc[5] += bf_hi(u.z)*w;
      acc[6] += bf_lo(u.w)*w; acc[7] += bf_hi(u.w)*w;
    }
    if (i < deg){
      int e = i + el_;
      float w = 0.f; uint4 u = make_uint4(0,0,0,0);
      if (e < deg){
        unsigned ee = (unsigned)(rs + e);
        int sb = srcp[ee];
        float x = el2[sb] + ern;
        x = x > 0.f ? x : 0.2f*x;
        w = __expf(x);
        u = fbase[((unsigned)sb << 3) + cbase + s];
      }
      Sacc += w;
      acc[0] += bf_lo(u.x)*w; acc[1] += bf_hi(u.x)*w;
      acc[2] += bf_lo(u.y)*w; acc[3] += bf_hi(u.y)*w;
      acc[4] += bf_lo(u.z)*w; acc[5] += bf_hi(u.z)*w;
      acc[6] += bf_lo(u.w)*w; acc[7] += bf_hi(u.w)*w;
    }

    // reduce across the 32 edge-lanes (bits 1..5), keep s fixed
    #pragma unroll
    for (int o = 2; o < 64; o <<= 1){
      #pragma unroll
      for (int k = 0; k < 8; k++) acc[k] += __shfl_xor(acc[k], o);
      Sacc += __shfl_xor(Sacc, o);
    }

    if (el_ == 0){                      // lanes 0..1 write 8 dims each (fp32)
      float inv = (deg > 0 && Sacc > 0.f) ? 1.f / Sacc : 0.f;
      int d0 = c*16 + s*8;
      float4 b0 = *(const float4*)&bias[d0];
      float4 b1 = *(const float4*)&bias[d0 + 4];
      float4 o0, o1;
      o0.x = acc[0]*inv + b0.x; o0.y = acc[1]*inv + b0.y;
      o0.z = acc[2]*inv + b0.z; o0.w = acc[3]*inv + b0.w;
      o1.x = acc[4]*inv + b1.x; o1.y = acc[5]*inv + b1.y;
      o1.z = acc[6]*inv + b1.z; o1.w = acc[7]*inv + b1.w;
      *(float4*)&out[(size_t)n*64 + d0] = o0;
      *(float4*)&out[(size_t)n*64 + d0 + 4] = o1;
    }

    if (nn >= N) break;
    n = nn; rs = rs_n; re = re_n;
  }
}

// ---------------- launch ----------------
extern "C" void kernel_launch(void* const* d_in, const int* in_sizes, int n_in,
                              void* d_out, int out_size, void* d_ws, size_t ws_size,
                              hipStream_t stream) {
  const float* emb = (const float*)d_in[0];
  const int*   src = (const int*)d_in[1];
  const int*   dst = (const int*)d_in[2];
  const float* W1  = (const float*)d_in[3];
  const float* al1 = (const float*)d_in[4];
  const float* ar1 = (const float*)d_in[5];
  const float* b1  = (const float*)d_in[6];
  const float* W2  = (const float*)d_in[7];
  const float* al2 = (const float*)d_in[8];
  const float* ar2 = (const float*)d_in[9];
  const float* b2  = (const float*)d_in[10];
  float* out = (float*)d_out;

  const int N = in_sizes[0] / 128;
  const int E = in_sizes[1];

  char* p = (char*)d_ws;
  auto alloc = [&](size_t bytes) -> void* {
    void* r = (void*)p; p += (bytes + 255) & ~(size_t)255; return r;
  };
  __hip_bfloat16* feat1b = (__hip_bfloat16*)alloc((size_t)N*256*2);
  __hip_bfloat16* h1b    = (__hip_bfloat16*)alloc((size_t)N*256*2);
  __hip_bfloat16* feat2b = (__hip_bfloat16*)alloc((size_t)N*64*2);
  float* el1             = (float*)alloc((size_t)N*4*4);
  float* er1             = (float*)alloc((size_t)N*4*4);
  float* el2             = (float*)alloc((size_t)N*4);
  float* er2             = (float*)alloc((size_t)N*4);
  int*   deg             = (int*)alloc((size_t)N*4);
  int*   row_start       = (int*)alloc((size_t)(N+1)*4);
  int*   cursor          = (int*)alloc((size_t)N*4);
  int*   blocksum        = (int*)alloc((size_t)DIV_UP(N,1024)*4);
  int*   srcp            = (int*)alloc((size_t)E*4);
  float* w4T             = (float*)alloc((size_t)E*4*4);

  const int nb = DIV_UP(N, 1024);
  const int gemmBlocks = DIV_UP(N, 64);
  const int cntBlocks  = DIV_UP(E, 256);

  // gath4s: 8 slices x 256 node-blocks = 2048 blocks; 1024 waves per slice
  const int g4nodeblk = 256;
  const int g4nwaves  = g4nodeblk * 4;
  // gath1s: 4 slices x 512 node-blocks = 2048 blocks; 2048 waves per slice
  const int g1nodeblk = 512;
  const int g1nwaves  = g1nodeblk * 4;

  hipMemsetAsync(deg, 0, (size_t)N*4, stream);

  k_gemm1_count<<<gemmBlocks + cntBlocks, 256, 0, stream>>>(
      emb, W1, (unsigned short*)feat1b, al1, ar1, el1, er1, N,
      dst, deg, E, gemmBlocks);

  k_scan1<<<nb, 256, 0, stream>>>(deg, blocksum, N);
  k_scan3<<<nb, 256, 0, stream>>>(deg, blocksum, nb, row_start, cursor, N);
  k_fillw4<<<DIV_UP(E,256), 256, 0, stream>>>(dst, src, cursor, srcp,
      (const float4*)el1, (const float4*)er1, w4T, E);

  k_gath4s<<<8 * g4nodeblk, 256, 0, stream>>>((const uint4*)feat1b, w4T, row_start,
                                              srcp, b1, h1b, N, E, g4nwaves);
  // Layer 2
  k_gemm_mfma<256,1,true><<<dim3(DIV_UP(N,64), 1), 256, 0, stream>>>(
      h1b, W2, 64, (unsigned short*)feat2b, al2, ar2, el2, er2, N);
  k_gath1s<<<4 * g1nodeblk, 256, 0, stream>>>((const uint4*)feat2b, el2, er2,
                                              row_start, srcp, b2, out, N, g1nwaves);
}

// Round 14
// 205.454 us; speedup vs baseline: 2.0698x; 2.0698x over previous
//
#include <hip/hip_runtime.h>
#include <hip/hip_bf16.h>
#include <math.h>

#define DIV_UP(a,b) (((a)+(b)-1)/(b))

typedef __attribute__((ext_vector_type(8))) short short8v;
typedef __attribute__((ext_vector_type(4))) float f32x4;

__device__ __forceinline__ float bf_lo(unsigned u){ union{unsigned x; float f;} v; v.x = u << 16; return v.f; }
__device__ __forceinline__ float bf_hi(unsigned u){ union{unsigned x; float f;} v; v.x = u & 0xffff0000u; return v.f; }
__device__ __forceinline__ unsigned short f2bf(float f){
  union{float f; unsigned u;} v; v.f = f;
  unsigned r = v.u + 0x7fff + ((v.u >> 16) & 1);   // round-nearest-even
  return (unsigned short)(r >> 16);
}
__device__ __forceinline__ unsigned packbf(float a, float b){
  return (unsigned)f2bf(a) | ((unsigned)f2bf(b) << 16);
}
__device__ __forceinline__ float lrelu(float x){ return x > 0.f ? x : 0.2f*x; }

// ---------------- CSR scan: single kernel, each block derives its own prefix ----------------
__global__ __launch_bounds__(256) void k_scan3(const int* __restrict__ deg,
                                               int* __restrict__ row_start,
                                               int* __restrict__ cursor, int N){
  int b = blockIdx.x;
  __shared__ int wsum2[4];
  __shared__ int s_boff;
  int lane = threadIdx.x & 63, wid = threadIdx.x >> 6;

  // prefix of this block: sum deg[0 .. b*1024) cooperatively (int4, aligned)
  int limit = b << 10;
  int acc = 0;
  for (int idx = (threadIdx.x << 2); idx < limit; idx += 1024){
    int4 v = *(const int4*)&deg[idx];
    acc += v.x + v.y + v.z + v.w;
  }
  #pragma unroll
  for (int o = 32; o; o >>= 1) acc += __shfl_down(acc, o);
  if (lane == 0) wsum2[wid] = acc;
  __syncthreads();
  if (threadIdx.x == 0) s_boff = wsum2[0] + wsum2[1] + wsum2[2] + wsum2[3];

  // local exclusive scan of this block's 1024 degrees
  int base = b*1024 + threadIdx.x*4;
  int v[4];
  #pragma unroll
  for (int i = 0; i < 4; i++){ int idx = base + i; v[i] = (idx < N) ? deg[idx] : 0; }
  int s = v[0] + v[1] + v[2] + v[3];
  int inc = s;
  #pragma unroll
  for (int o = 1; o < 64; o <<= 1){ int t = __shfl_up(inc, o); if (lane >= o) inc += t; }
  __shared__ int wsum[4];
  if (lane == 63) wsum[wid] = inc;
  __syncthreads();
  int woff = 0;
  #pragma unroll
  for (int i = 0; i < 4; i++) if (i < wid) woff += wsum[i];
  int run = s_boff + woff + inc - s;
  #pragma unroll
  for (int i = 0; i < 4; i++){
    int idx = base + i;
    if (idx < N){ row_start[idx] = run; cursor[idx] = run; run += v[i]; }
  }
  if (base < N && base + 4 >= N) row_start[N] = run;
}

// fill + layer-1 edge weights fused: one pass over original edges.
__global__ void k_fillw4(const int* __restrict__ dst, const int* __restrict__ src,
                         int* __restrict__ cursor, int* __restrict__ srcp,
                         const float4* __restrict__ el4, const float4* __restrict__ er4,
                         float4* __restrict__ w4, int E){
  int i = blockIdx.x*blockDim.x + threadIdx.x;
  if (i < E){
    int d = dst[i], s = src[i];
    int p = atomicAdd(&cursor[d], 1);
    srcp[p] = s;
    float4 l = el4[s], r = er4[d];
    float4 w;
    w.x = __expf(lrelu(l.x + r.x));
    w.y = __expf(lrelu(l.y + r.y));
    w.z = __expf(lrelu(l.z + r.z));
    w.w = __expf(lrelu(l.w + r.w));
    w4[p] = w;
  }
}

// ---------------- GEMM1 (A staged once, 4-head loop) fused with degree count ----------------
// blocks [0, gemmBlocks): GEMM1 64-row tile.  blocks [gemmBlocks, ...): count_deg.
__global__ __launch_bounds__(256) void k_gemm1_count(const float* __restrict__ A, // emb [M][128]
      const float* __restrict__ B,      // W1 [128][256]
      unsigned short* __restrict__ Cbf, // feat1b [M][256]
      const float* __restrict__ al, const float* __restrict__ ar,   // [256]
      float* __restrict__ el, float* __restrict__ er, int M,        // [M][4]
      const int* __restrict__ dst, int* __restrict__ deg, int E, int gemmBlocks){
  __shared__ alignas(16) __hip_bfloat16 At[64][136];
  __shared__ alignas(16) __hip_bfloat16 Bt[64][136];
  __shared__ float elp[2][64], erp[2][64];

  if (blockIdx.x >= gemmBlocks){
    int i = (blockIdx.x - gemmBlocks)*256 + threadIdx.x;
    if (i < E) atomicAdd(&deg[dst[i]], 1);
    return;
  }

  const int tid = threadIdx.x;
  const int lane = tid & 63, w = tid >> 6;
  const int mw = w >> 1, nw = w & 1;
  const int m0 = blockIdx.x * 64;
  const int rbase = mw*32, cbase = nw*32;
  const int fr = lane & 15, fg = lane >> 4;

  // stage A once: 64 x 128 fp32 -> bf16
  #pragma unroll
  for (int i = 0; i < 8; i++){
    int q = tid + i*256;
    int row = q >> 5, c4 = q & 31;
    float4 a = make_float4(0.f,0.f,0.f,0.f);
    if (m0 + row < M) a = *(const float4*)&A[(size_t)(m0+row)*128 + c4*4];
    *(uint2*)&At[row][c4*4] = make_uint2(packbf(a.x,a.y), packbf(a.z,a.w));
  }

  for (int by = 0; by < 4; by++){
    int n0 = by * 64;
    __syncthreads();                    // A staged / prev iter's Bt+elp reads done
    #pragma unroll
    for (int i = 0; i < 8; i++){        // Bt[c][k] = W1[k][n0+c]
      int q = tid + i*256;
      int c = q & 63, k4 = q >> 6;
      float b0 = B[(size_t)(k4*4+0)*256 + n0 + c];
      float b1 = B[(size_t)(k4*4+1)*256 + n0 + c];
      float b2 = B[(size_t)(k4*4+2)*256 + n0 + c];
      float b3 = B[(size_t)(k4*4+3)*256 + n0 + c];
      *(uint2*)&Bt[c][k4*4] = make_uint2(packbf(b0,b1), packbf(b2,b3));
    }
    __syncthreads();

    f32x4 acc[2][2];
    #pragma unroll
    for (int i = 0; i < 2; i++)
      #pragma unroll
      for (int jj = 0; jj < 2; jj++)
        #pragma unroll
        for (int r = 0; r < 4; r++) acc[i][jj][r] = 0.f;

    #pragma unroll
    for (int ks = 0; ks < 4; ks++){
      short8v a0 = *(const short8v*)&At[rbase + fr     ][ks*32 + fg*8];
      short8v a1 = *(const short8v*)&At[rbase + 16 + fr][ks*32 + fg*8];
      short8v b0 = *(const short8v*)&Bt[cbase + fr     ][ks*32 + fg*8];
      short8v b1 = *(const short8v*)&Bt[cbase + 16 + fr][ks*32 + fg*8];
      acc[0][0] = __builtin_amdgcn_mfma_f32_16x16x32_bf16(a0, b0, acc[0][0], 0,0,0);
      acc[0][1] = __builtin_amdgcn_mfma_f32_16x16x32_bf16(a0, b1, acc[0][1], 0,0,0);
      acc[1][0] = __builtin_amdgcn_mfma_f32_16x16x32_bf16(a1, b0, acc[1][0], 0,0,0);
      acc[1][1] = __builtin_amdgcn_mfma_f32_16x16x32_bf16(a1, b1, acc[1][1], 0,0,0);
    }

    float alv[2], arv[2];
    #pragma unroll
    for (int nt = 0; nt < 2; nt++){
      int col = cbase + nt*16 + fr;
      alv[nt] = al[n0 + col];
      arv[nt] = ar[n0 + col];
    }
    #pragma unroll
    for (int mt = 0; mt < 2; mt++){
      #pragma unroll
      for (int r = 0; r < 4; r++){
        float pl = acc[mt][0][r]*alv[0] + acc[mt][1][r]*alv[1];
        float pr = acc[mt][0][r]*arv[0] + acc[mt][1][r]*arv[1];
        #pragma unroll
        for (int o = 1; o < 16; o <<= 1){ pl += __shfl_xor(pl, o); pr += __shfl_xor(pr, o); }
        if (fr == 0){
          int rl = rbase + mt*16 + fg*4 + r;
          elp[nw][rl] = pl; erp[nw][rl] = pr;
        }
      }
    }
    #pragma unroll
    for (int mt = 0; mt < 2; mt++){
      #pragma unroll
      for (int r = 0; r < 4; r++){
        int row = m0 + rbase + mt*16 + fg*4 + r;
        if (row < M){
          #pragma unroll
          for (int nt = 0; nt < 2; nt++)
            Cbf[(size_t)row*256 + n0 + cbase + nt*16 + fr] = f2bf(acc[mt][nt][r]);
        }
      }
    }
    __syncthreads();
    if (tid < 64){
      int row = m0 + tid;
      if (row < M){
        el[(size_t)row*4 + by] = elp[0][tid] + elp[1][tid];
        er[(size_t)row*4 + by] = erp[0][tid] + erp[1][tid];
      }
    }
  }
}

// ---------------- GEMM2 (layer 2), 64x64, full-K LDS, fused el/er ----------------
template<int K, int H, bool ABF>
__global__ __launch_bounds__(256) void k_gemm_mfma(const void* __restrict__ Av,
      const float* __restrict__ B, int ldb,
      unsigned short* __restrict__ Cbf,
      const float* __restrict__ al, const float* __restrict__ ar,
      float* __restrict__ el, float* __restrict__ er, int M){
  constexpr int KP = K + 8;
  __shared__ alignas(16) __hip_bfloat16 At[64][KP];
  __shared__ alignas(16) __hip_bfloat16 Bt[64][KP];
  __shared__ float elp[2][64], erp[2][64];
  const int tid = threadIdx.x;
  const int lane = tid & 63, w = tid >> 6;
  const int mw = w >> 1, nw = w & 1;
  const int m0 = blockIdx.x * 64, by = blockIdx.y, n0 = by * 64;

  if constexpr (!ABF){
    const float* A = (const float*)Av;
    #pragma unroll
    for (int i = 0; i < K/16; i++){
      int q = tid + i*256;
      int row = q / (K/4), c4 = q % (K/4);
      float4 a = make_float4(0.f,0.f,0.f,0.f);
      if (m0 + row < M) a = *(const float4*)&A[(size_t)(m0+row)*K + c4*4];
      *(uint2*)&At[row][c4*4] = make_uint2(packbf(a.x,a.y), packbf(a.z,a.w));
    }
  } else {
    const __hip_bfloat16* A = (const __hip_bfloat16*)Av;
    #pragma unroll
    for (int i = 0; i < K/32; i++){
      int q = tid + i*256;
      int row = q / (K/8), c8 = q % (K/8);
      uint4 u = make_uint4(0,0,0,0);
      if (m0 + row < M) u = *(const uint4*)&A[(size_t)(m0+row)*K + c8*8];
      *(uint4*)&At[row][c8*8] = u;
    }
  }
  #pragma unroll
  for (int i = 0; i < K/16; i++){
    int q = tid + i*256;
    int c = q & 63, k4 = q >> 6;
    float b0 = B[(size_t)(k4*4+0)*ldb + n0 + c];
    float b1 = B[(size_t)(k4*4+1)*ldb + n0 + c];
    float b2 = B[(size_t)(k4*4+2)*ldb + n0 + c];
    float b3 = B[(size_t)(k4*4+3)*ldb + n0 + c];
    *(uint2*)&Bt[c][k4*4] = make_uint2(packbf(b0,b1), packbf(b2,b3));
  }
  __syncthreads();

  f32x4 acc[2][2];
  #pragma unroll
  for (int i = 0; i < 2; i++)
    #pragma unroll
    for (int j = 0; j < 2; j++)
      #pragma unroll
      for (int r = 0; r < 4; r++) acc[i][j][r] = 0.f;

  const int rbase = mw*32, cbase = nw*32;
  const int fr = lane & 15, fg = lane >> 4;
  #pragma unroll
  for (int ks = 0; ks < K/32; ks++){
    short8v a0 = *(const short8v*)&At[rbase + fr     ][ks*32 + fg*8];
    short8v a1 = *(const short8v*)&At[rbase + 16 + fr][ks*32 + fg*8];
    short8v b0 = *(const short8v*)&Bt[cbase + fr     ][ks*32 + fg*8];
    short8v b1 = *(const short8v*)&Bt[cbase + 16 + fr][ks*32 + fg*8];
    acc[0][0] = __builtin_amdgcn_mfma_f32_16x16x32_bf16(a0, b0, acc[0][0], 0,0,0);
    acc[0][1] = __builtin_amdgcn_mfma_f32_16x16x32_bf16(a0, b1, acc[0][1], 0,0,0);
    acc[1][0] = __builtin_amdgcn_mfma_f32_16x16x32_bf16(a1, b0, acc[1][0], 0,0,0);
    acc[1][1] = __builtin_amdgcn_mfma_f32_16x16x32_bf16(a1, b1, acc[1][1], 0,0,0);
  }

  float alv[2], arv[2];
  #pragma unroll
  for (int nt = 0; nt < 2; nt++){
    int col = cbase + nt*16 + fr;
    alv[nt] = al[by*64 + col];
    arv[nt] = ar[by*64 + col];
  }
  #pragma unroll
  for (int mt = 0; mt < 2; mt++){
    #pragma unroll
    for (int r = 0; r < 4; r++){
      float pl = acc[mt][0][r]*alv[0] + acc[mt][1][r]*alv[1];
      float pr = acc[mt][0][r]*arv[0] + acc[mt][1][r]*arv[1];
      #pragma unroll
      for (int o = 1; o < 16; o <<= 1){ pl += __shfl_xor(pl, o); pr += __shfl_xor(pr, o); }
      if (fr == 0){
        int rl = rbase + mt*16 + fg*4 + r;
        elp[nw][rl] = pl; erp[nw][rl] = pr;
      }
    }
  }
  const int NN = H*64;
  #pragma unroll
  for (int mt = 0; mt < 2; mt++){
    #pragma unroll
    for (int r = 0; r < 4; r++){
      int row = m0 + rbase + mt*16 + fg*4 + r;
      if (row < M){
        #pragma unroll
        for (int nt = 0; nt < 2; nt++)
          Cbf[(size_t)row*NN + n0 + cbase + nt*16 + fr] = f2bf(acc[mt][nt][r]);
      }
    }
  }
  __syncthreads();
  if (tid < 64){
    int row = m0 + tid;
    if (row < M){
      el[(size_t)row*H + by] = elp[0][tid] + elp[1][tid];
      er[(size_t)row*H + by] = erp[0][tid] + erp[1][tid];
    }
  }
}

// ---------------- pure gather-aggregate, H=4 (layer 1), grid-stride, 32-bit addr ----------------
__global__ __launch_bounds__(256) void k_gath4(const uint4* __restrict__ fbase, // bf16 [N][256] as uint4[N*32]
      const float* __restrict__ w4, const int* __restrict__ row_start,
      const int* __restrict__ srcp, const float* __restrict__ bias,
      __hip_bfloat16* __restrict__ outb, int N, int nwaves){
  int wv = threadIdx.x >> 6, lane = threadIdx.x & 63;
  int g = lane >> 4, j = lane & 15, h = j >> 2;
  const unsigned jo2 = (unsigned)(j << 1);   // uint4 index within row (2 per lane)

  int n = blockIdx.x*4 + wv;
  if (n >= N) return;
  int rs = row_start[n], re = row_start[n+1];

  while (true){
    int deg = re - rs;
    int nn = n + nwaves;
    int rs_n = 0, re_n = 0;
    if (nn < N){ rs_n = row_start[nn]; re_n = row_start[nn+1]; }  // prefetch next node

    float acc[16];
    #pragma unroll
    for (int k = 0; k < 16; k++) acc[k] = 0.f;
    float Sacc = 0.f;

    int i = 0;
    int full = deg & ~15;          // unguarded 16-edge quads
    for (; i < full; i += 16){
      float wb[4]; uint4 u0[4], u1[4];
      #pragma unroll
      for (int k = 0; k < 4; k++){
        unsigned e = (unsigned)(rs + i + k*4 + g);
        int sb = srcp[e];
        wb[k] = w4[(e << 2) + h];
        unsigned fi = ((unsigned)sb << 5) + jo2;
        u0[k] = fbase[fi];
        u1[k] = fbase[fi + 1];
      }
      #pragma unroll
      for (int k = 0; k < 4; k++){
        float wk = wb[k];
        Sacc += wk;
        acc[0]  += bf_lo(u0[k].x)*wk; acc[1]  += bf_hi(u0[k].x)*wk;
        acc[2]  += bf_lo(u0[k].y)*wk; acc[3]  += bf_hi(u0[k].y)*wk;
        acc[4]  += bf_lo(u0[k].z)*wk; acc[5]  += bf_hi(u0[k].z)*wk;
        acc[6]  += bf_lo(u0[k].w)*wk; acc[7]  += bf_hi(u0[k].w)*wk;
        acc[8]  += bf_lo(u1[k].x)*wk; acc[9]  += bf_hi(u1[k].x)*wk;
        acc[10] += bf_lo(u1[k].y)*wk; acc[11] += bf_hi(u1[k].y)*wk;
        acc[12] += bf_lo(u1[k].z)*wk; acc[13] += bf_hi(u1[k].z)*wk;
        acc[14] += bf_lo(u1[k].w)*wk; acc[15] += bf_hi(u1[k].w)*wk;
      }
    }
    if (i < deg){                  // guarded tail (<=15 edges)
      float wb[4]; uint4 u0[4], u1[4];
      #pragma unroll
      for (int k = 0; k < 4; k++){
        int e = i + k*4 + g;
        wb[k] = 0.f;
        u0[k] = make_uint4(0,0,0,0); u1[k] = make_uint4(0,0,0,0);
        if (e < deg){
          unsigned ee = (unsigned)(rs + e);
          int sb = srcp[ee];
          wb[k] = w4[(ee << 2) + h];
          unsigned fi = ((unsigned)sb << 5) + jo2;
          u0[k] = fbase[fi];
          u1[k] = fbase[fi + 1];
        }
      }
      #pragma unroll
      for (int k = 0; k < 4; k++){
        float wk = wb[k];
        Sacc += wk;
        acc[0]  += bf_lo(u0[k].x)*wk; acc[1]  += bf_hi(u0[k].x)*wk;
        acc[2]  += bf_lo(u0[k].y)*wk; acc[3]  += bf_hi(u0[k].y)*wk;
        acc[4]  += bf_lo(u0[k].z)*wk; acc[5]  += bf_hi(u0[k].z)*wk;
        acc[6]  += bf_lo(u0[k].w)*wk; acc[7]  += bf_hi(u0[k].w)*wk;
        acc[8]  += bf_lo(u1[k].x)*wk; acc[9]  += bf_hi(u1[k].x)*wk;
        acc[10] += bf_lo(u1[k].y)*wk; acc[11] += bf_hi(u1[k].y)*wk;
        acc[12] += bf_lo(u1[k].z)*wk; acc[13] += bf_hi(u1[k].z)*wk;
        acc[14] += bf_lo(u1[k].w)*wk; acc[15] += bf_hi(u1[k].w)*wk;
      }
    }

    #pragma unroll
    for (int k = 0; k < 16; k++){
      acc[k] += __shfl_xor(acc[k], 16);
      acc[k] += __shfl_xor(acc[k], 32);
    }
    Sacc += __shfl_xor(Sacc, 16);
    Sacc += __shfl_xor(Sacc, 32);
    if (g == 0){
      float inv = (deg > 0 && Sacc > 0.f) ? 1.f / Sacc : 0.f;
      float4 b0 = *(const float4*)&bias[j*16 + 0];
      float4 b1 = *(const float4*)&bias[j*16 + 4];
      float4 b2 = *(const float4*)&bias[j*16 + 8];
      float4 b3 = *(const float4*)&bias[j*16 + 12];
      float v[16];
      v[0]=acc[0]*inv+b0.x;  v[1]=acc[1]*inv+b0.y;  v[2]=acc[2]*inv+b0.z;  v[3]=acc[3]*inv+b0.w;
      v[4]=acc[4]*inv+b1.x;  v[5]=acc[5]*inv+b1.y;  v[6]=acc[6]*inv+b1.z;  v[7]=acc[7]*inv+b1.w;
      v[8]=acc[8]*inv+b2.x;  v[9]=acc[9]*inv+b2.y;  v[10]=acc[10]*inv+b2.z; v[11]=acc[11]*inv+b2.w;
      v[12]=acc[12]*inv+b3.x; v[13]=acc[13]*inv+b3.y; v[14]=acc[14]*inv+b3.z; v[15]=acc[15]*inv+b3.w;
      #pragma unroll
      for (int k = 0; k < 16; k++) v[k] = fmaxf(v[k], 0.f);   // relu (layer 1)
      uint4 o0, o1;
      o0.x = packbf(v[0], v[1]);   o0.y = packbf(v[2], v[3]);
      o0.z = packbf(v[4], v[5]);   o0.w = packbf(v[6], v[7]);
      o1.x = packbf(v[8], v[9]);   o1.y = packbf(v[10], v[11]);
      o1.z = packbf(v[12], v[13]); o1.w = packbf(v[14], v[15]);
      uint4* op = (uint4*)outb + (size_t)n*32 + (j << 1);
      op[0] = o0; op[1] = o1;
    }

    if (nn >= N) break;
    n = nn; rs = rs_n; re = re_n;
  }
}

// ---------------- gather-aggregate, H=1 (layer 2), inline weights, fp32 out ----------------
__global__ __launch_bounds__(256) void k_gath1(const uint2* __restrict__ fbase, // bf16 [N][64] as uint2[N*16]
      const float* __restrict__ el2, const float* __restrict__ er2,
      const int* __restrict__ row_start, const int* __restrict__ srcp,
      const float* __restrict__ bias, float* __restrict__ out, int N, int nwaves){
  int wv = threadIdx.x >> 6, lane = threadIdx.x & 63;
  int g = lane >> 4, j = lane & 15;
  const unsigned jo = (unsigned)j;

  int n = blockIdx.x*4 + wv;
  if (n >= N) return;
  int rs = row_start[n], re = row_start[n+1];

  while (true){
    int deg = re - rs;
    int nn = n + nwaves;
    int rs_n = 0, re_n = 0;
    if (nn < N){ rs_n = row_start[nn]; re_n = row_start[nn+1]; }

    float ern = er2[n];
    float acc[4] = {0.f, 0.f, 0.f, 0.f};
    float Sacc = 0.f;

    int i = 0;
    int full = deg & ~15;
    for (; i < full; i += 16){
      float wb[4]; uint2 u[4];
      #pragma unroll
      for (int k = 0; k < 4; k++){
        unsigned e = (unsigned)(rs + i + k*4 + g);
        int sb = srcp[e];                       // broadcast within 16-lane group
        float x = el2[sb] + ern;                // broadcast
        x = x > 0.f ? x : 0.2f*x;
        wb[k] = __expf(x);
        u[k] = fbase[((unsigned)sb << 4) + jo];
      }
      #pragma unroll
      for (int k = 0; k < 4; k++){
        float wk = wb[k];
        Sacc += wk;
        acc[0] += bf_lo(u[k].x)*wk; acc[1] += bf_hi(u[k].x)*wk;
        acc[2] += bf_lo(u[k].y)*wk; acc[3] += bf_hi(u[k].y)*wk;
      }
    }
    if (i < deg){
      float wb[4]; uint2 u[4];
      #pragma unroll
      for (int k = 0; k < 4; k++){
        int e = i + k*4 + g;
        wb[k] = 0.f;
        u[k] = make_uint2(0,0);
        if (e < deg){
          unsigned ee = (unsigned)(rs + e);
          int sb = srcp[ee];
          float x = el2[sb] + ern;
          x = x > 0.f ? x : 0.2f*x;
          wb[k] = __expf(x);
          u[k] = fbase[((unsigned)sb << 4) + jo];
        }
      }
      #pragma unroll
      for (int k = 0; k < 4; k++){
        float wk = wb[k];
        Sacc += wk;
        acc[0] += bf_lo(u[k].x)*wk; acc[1] += bf_hi(u[k].x)*wk;
        acc[2] += bf_lo(u[k].y)*wk; acc[3] += bf_hi(u[k].y)*wk;
      }
    }

    #pragma unroll
    for (int k = 0; k < 4; k++){
      acc[k] += __shfl_xor(acc[k], 16);
      acc[k] += __shfl_xor(acc[k], 32);
    }
    Sacc += __shfl_xor(Sacc, 16);
    Sacc += __shfl_xor(Sacc, 32);
    if (g == 0){
      float inv = (deg > 0 && Sacc > 0.f) ? 1.f / Sacc : 0.f;
      float4 b = *(const float4*)&bias[j*4];
      float4 o;
      o.x = acc[0]*inv + b.x; o.y = acc[1]*inv + b.y;
      o.z = acc[2]*inv + b.z; o.w = acc[3]*inv + b.w;
      *(float4*)&out[(size_t)n*64 + j*4] = o;
    }

    if (nn >= N) break;
    n = nn; rs = rs_n; re = re_n;
  }
}

// ---------------- launch ----------------
extern "C" void kernel_launch(void* const* d_in, const int* in_sizes, int n_in,
                              void* d_out, int out_size, void* d_ws, size_t ws_size,
                              hipStream_t stream) {
  const float* emb = (const float*)d_in[0];
  const int*   src = (const int*)d_in[1];
  const int*   dst = (const int*)d_in[2];
  const float* W1  = (const float*)d_in[3];
  const float* al1 = (const float*)d_in[4];
  const float* ar1 = (const float*)d_in[5];
  const float* b1  = (const float*)d_in[6];
  const float* W2  = (const float*)d_in[7];
  const float* al2 = (const float*)d_in[8];
  const float* ar2 = (const float*)d_in[9];
  const float* b2  = (const float*)d_in[10];
  float* out = (float*)d_out;

  const int N = in_sizes[0] / 128;
  const int E = in_sizes[1];

  char* p = (char*)d_ws;
  auto alloc = [&](size_t bytes) -> void* {
    void* r = (void*)p; p += (bytes + 255) & ~(size_t)255; return r;
  };
  __hip_bfloat16* feat1b = (__hip_bfloat16*)alloc((size_t)N*256*2);
  __hip_bfloat16* h1b    = (__hip_bfloat16*)alloc((size_t)N*256*2);
  __hip_bfloat16* feat2b = (__hip_bfloat16*)alloc((size_t)N*64*2);
  float* el1             = (float*)alloc((size_t)N*4*4);
  float* er1             = (float*)alloc((size_t)N*4*4);
  float* el2             = (float*)alloc((size_t)N*4);
  float* er2             = (float*)alloc((size_t)N*4);
  int*   deg             = (int*)alloc((size_t)N*4);
  int*   row_start       = (int*)alloc((size_t)(N+1)*4);
  int*   cursor          = (int*)alloc((size_t)N*4);
  int*   srcp            = (int*)alloc((size_t)E*4);
  float* w4              = (float*)alloc((size_t)E*16);

  const int nb = DIV_UP(N, 1024);
  const int gblocks = min(DIV_UP(N, 4), 2048);
  const int nwaves  = gblocks * 4;
  const int gemmBlocks = DIV_UP(N, 64);
  const int cntBlocks  = DIV_UP(E, 256);

  hipMemsetAsync(deg, 0, (size_t)N*4, stream);

  // GEMM1 (layer-1 features + el1/er1) fused with degree count (independent work)
  k_gemm1_count<<<gemmBlocks + cntBlocks, 256, 0, stream>>>(
      emb, W1, (unsigned short*)feat1b, al1, ar1, el1, er1, N,
      dst, deg, E, gemmBlocks);

  k_scan3<<<nb, 256, 0, stream>>>(deg, row_start, cursor, N);
  k_fillw4<<<DIV_UP(E,256), 256, 0, stream>>>(dst, src, cursor, srcp,
      (const float4*)el1, (const float4*)er1, (float4*)w4, E);

  k_gath4<<<gblocks, 256, 0, stream>>>((const uint4*)feat1b, w4, row_start,
                                       srcp, b1, h1b, N, nwaves);
  // Layer 2
  k_gemm_mfma<256,1,true><<<dim3(DIV_UP(N,64), 1), 256, 0, stream>>>(
      h1b, W2, 64, (unsigned short*)feat2b, al2, ar2, el2, er2, N);
  k_gath1<<<gblocks, 256, 0, stream>>>((const uint2*)feat2b, el2, er2,
                                       row_start, srcp, b2, out, N, nwaves);
}

// Round 15
// 199.599 us; speedup vs baseline: 2.1306x; 1.0293x over previous
//
#include <hip/hip_runtime.h>
#include <hip/hip_bf16.h>
#include <math.h>

#define DIV_UP(a,b) (((a)+(b)-1)/(b))

typedef __attribute__((ext_vector_type(8))) short short8v;
typedef __attribute__((ext_vector_type(4))) float f32x4;

__device__ __forceinline__ float bf_lo(unsigned u){ union{unsigned x; float f;} v; v.x = u << 16; return v.f; }
__device__ __forceinline__ float bf_hi(unsigned u){ union{unsigned x; float f;} v; v.x = u & 0xffff0000u; return v.f; }
__device__ __forceinline__ unsigned short f2bf(float f){
  union{float f; unsigned u;} v; v.f = f;
  unsigned r = v.u + 0x7fff + ((v.u >> 16) & 1);   // round-nearest-even
  return (unsigned short)(r >> 16);
}
__device__ __forceinline__ unsigned packbf(float a, float b){
  return (unsigned)f2bf(a) | ((unsigned)f2bf(b) << 16);
}
__device__ __forceinline__ float lrelu(float x){ return x > 0.f ? x : 0.2f*x; }

// ---------------- CSR scan (two-stage, R12-proven) ----------------
__global__ __launch_bounds__(256) void k_scan1(const int* __restrict__ deg,
                                               int* __restrict__ blocksum, int N){
  int b = blockIdx.x;
  int base = b*1024 + threadIdx.x*4;
  int s = 0;
  if (base + 3 < N){
    int4 v = *(const int4*)&deg[base];
    s = v.x + v.y + v.z + v.w;
  } else {
    for (int i = 0; i < 4; i++){ int idx = base + i; if (idx < N) s += deg[idx]; }
  }
  #pragma unroll
  for (int o = 32; o; o >>= 1) s += __shfl_down(s, o);
  __shared__ int ws[4];
  int wid = threadIdx.x >> 6, lane = threadIdx.x & 63;
  if (lane == 0) ws[wid] = s;
  __syncthreads();
  if (threadIdx.x == 0) blocksum[b] = ws[0] + ws[1] + ws[2] + ws[3];
}

// scan3: computes own block offset from raw blocksums (nb small), then local scan.
__global__ __launch_bounds__(256) void k_scan3(const int* __restrict__ deg,
                                               const int* __restrict__ blocksum, int nb,
                                               int* __restrict__ row_start,
                                               int* __restrict__ cursor, int N){
  int b = blockIdx.x;
  __shared__ int s_boff;
  if (threadIdx.x < 64){
    int acc = 0;
    for (int base = 0; base < nb; base += 64){
      int idx = base + threadIdx.x;
      if (idx < nb && idx < b) acc += blocksum[idx];
    }
    #pragma unroll
    for (int o = 32; o; o >>= 1) acc += __shfl_down(acc, o);
    if (threadIdx.x == 0) s_boff = acc;
  }
  int base = b*1024 + threadIdx.x*4;
  int v[4];
  #pragma unroll
  for (int i = 0; i < 4; i++){ int idx = base + i; v[i] = (idx < N) ? deg[idx] : 0; }
  int s = v[0] + v[1] + v[2] + v[3];
  int lane = threadIdx.x & 63, wid = threadIdx.x >> 6;
  int inc = s;
  #pragma unroll
  for (int o = 1; o < 64; o <<= 1){ int t = __shfl_up(inc, o); if (lane >= o) inc += t; }
  __shared__ int wsum[4];
  if (lane == 63) wsum[wid] = inc;
  __syncthreads();
  int woff = 0;
  #pragma unroll
  for (int i = 0; i < 4; i++) if (i < wid) woff += wsum[i];
  int run = s_boff + woff + inc - s;
  #pragma unroll
  for (int i = 0; i < 4; i++){
    int idx = base + i;
    if (idx < N){ row_start[idx] = run; cursor[idx] = run; run += v[i]; }
  }
  if (base < N && base + 4 >= N) row_start[N] = run;
}

// fill + layer-1 edge weights fused: one pass over original edges.
__global__ void k_fillw4(const int* __restrict__ dst, const int* __restrict__ src,
                         int* __restrict__ cursor, int* __restrict__ srcp,
                         const float4* __restrict__ el4, const float4* __restrict__ er4,
                         float4* __restrict__ w4, int E){
  int i = blockIdx.x*blockDim.x + threadIdx.x;
  if (i < E){
    int d = dst[i], s = src[i];
    int p = atomicAdd(&cursor[d], 1);
    srcp[p] = s;
    float4 l = el4[s], r = er4[d];
    float4 w;
    w.x = __expf(lrelu(l.x + r.x));
    w.y = __expf(lrelu(l.y + r.y));
    w.z = __expf(lrelu(l.z + r.z));
    w.w = __expf(lrelu(l.w + r.w));
    w4[p] = w;
  }
}

// ---------------- GEMM1 (A staged once, 4-head loop) fused with degree count ----------------
// blocks [0, gemmBlocks): GEMM1 64-row tile.  blocks [gemmBlocks, ...): count_deg.
__global__ __launch_bounds__(256) void k_gemm1_count(const float* __restrict__ A, // emb [M][128]
      const float* __restrict__ B,      // W1 [128][256]
      unsigned short* __restrict__ Cbf, // feat1b [M][256]
      const float* __restrict__ al, const float* __restrict__ ar,   // [256]
      float* __restrict__ el, float* __restrict__ er, int M,        // [M][4]
      const int* __restrict__ dst, int* __restrict__ deg, int E, int gemmBlocks){
  __shared__ alignas(16) __hip_bfloat16 At[64][136];
  __shared__ alignas(16) __hip_bfloat16 Bt[64][136];
  __shared__ float elp[2][64], erp[2][64];

  if (blockIdx.x >= gemmBlocks){
    int i = (blockIdx.x - gemmBlocks)*256 + threadIdx.x;
    if (i < E) atomicAdd(&deg[dst[i]], 1);
    return;
  }

  const int tid = threadIdx.x;
  const int lane = tid & 63, w = tid >> 6;
  const int mw = w >> 1, nw = w & 1;
  const int m0 = blockIdx.x * 64;
  const int rbase = mw*32, cbase = nw*32;
  const int fr = lane & 15, fg = lane >> 4;

  // stage A once: 64 x 128 fp32 -> bf16
  #pragma unroll
  for (int i = 0; i < 8; i++){
    int q = tid + i*256;
    int row = q >> 5, c4 = q & 31;
    float4 a = make_float4(0.f,0.f,0.f,0.f);
    if (m0 + row < M) a = *(const float4*)&A[(size_t)(m0+row)*128 + c4*4];
    *(uint2*)&At[row][c4*4] = make_uint2(packbf(a.x,a.y), packbf(a.z,a.w));
  }

  for (int by = 0; by < 4; by++){
    int n0 = by * 64;
    __syncthreads();                    // A staged / prev iter's Bt+elp reads done
    #pragma unroll
    for (int i = 0; i < 8; i++){        // Bt[c][k] = W1[k][n0+c]
      int q = tid + i*256;
      int c = q & 63, k4 = q >> 6;
      float b0 = B[(size_t)(k4*4+0)*256 + n0 + c];
      float b1 = B[(size_t)(k4*4+1)*256 + n0 + c];
      float b2 = B[(size_t)(k4*4+2)*256 + n0 + c];
      float b3 = B[(size_t)(k4*4+3)*256 + n0 + c];
      *(uint2*)&Bt[c][k4*4] = make_uint2(packbf(b0,b1), packbf(b2,b3));
    }
    __syncthreads();

    f32x4 acc[2][2];
    #pragma unroll
    for (int i = 0; i < 2; i++)
      #pragma unroll
      for (int jj = 0; jj < 2; jj++)
        #pragma unroll
        for (int r = 0; r < 4; r++) acc[i][jj][r] = 0.f;

    #pragma unroll
    for (int ks = 0; ks < 4; ks++){
      short8v a0 = *(const short8v*)&At[rbase + fr     ][ks*32 + fg*8];
      short8v a1 = *(const short8v*)&At[rbase + 16 + fr][ks*32 + fg*8];
      short8v b0 = *(const short8v*)&Bt[cbase + fr     ][ks*32 + fg*8];
      short8v b1 = *(const short8v*)&Bt[cbase + 16 + fr][ks*32 + fg*8];
      acc[0][0] = __builtin_amdgcn_mfma_f32_16x16x32_bf16(a0, b0, acc[0][0], 0,0,0);
      acc[0][1] = __builtin_amdgcn_mfma_f32_16x16x32_bf16(a0, b1, acc[0][1], 0,0,0);
      acc[1][0] = __builtin_amdgcn_mfma_f32_16x16x32_bf16(a1, b0, acc[1][0], 0,0,0);
      acc[1][1] = __builtin_amdgcn_mfma_f32_16x16x32_bf16(a1, b1, acc[1][1], 0,0,0);
    }

    float alv[2], arv[2];
    #pragma unroll
    for (int nt = 0; nt < 2; nt++){
      int col = cbase + nt*16 + fr;
      alv[nt] = al[n0 + col];
      arv[nt] = ar[n0 + col];
    }
    #pragma unroll
    for (int mt = 0; mt < 2; mt++){
      #pragma unroll
      for (int r = 0; r < 4; r++){
        float pl = acc[mt][0][r]*alv[0] + acc[mt][1][r]*alv[1];
        float pr = acc[mt][0][r]*arv[0] + acc[mt][1][r]*arv[1];
        #pragma unroll
        for (int o = 1; o < 16; o <<= 1){ pl += __shfl_xor(pl, o); pr += __shfl_xor(pr, o); }
        if (fr == 0){
          int rl = rbase + mt*16 + fg*4 + r;
          elp[nw][rl] = pl; erp[nw][rl] = pr;
        }
      }
    }
    #pragma unroll
    for (int mt = 0; mt < 2; mt++){
      #pragma unroll
      for (int r = 0; r < 4; r++){
        int row = m0 + rbase + mt*16 + fg*4 + r;
        if (row < M){
          #pragma unroll
          for (int nt = 0; nt < 2; nt++)
            Cbf[(size_t)row*256 + n0 + cbase + nt*16 + fr] = f2bf(acc[mt][nt][r]);
        }
      }
    }
    __syncthreads();
    if (tid < 64){
      int row = m0 + tid;
      if (row < M){
        el[(size_t)row*4 + by] = elp[0][tid] + elp[1][tid];
        er[(size_t)row*4 + by] = erp[0][tid] + erp[1][tid];
      }
    }
  }
}

// ---------------- GEMM2 (layer 2), 64x64, full-K LDS, fused el/er ----------------
template<int K, int H, bool ABF>
__global__ __launch_bounds__(256) void k_gemm_mfma(const void* __restrict__ Av,
      const float* __restrict__ B, int ldb,
      unsigned short* __restrict__ Cbf,
      const float* __restrict__ al, const float* __restrict__ ar,
      float* __restrict__ el, float* __restrict__ er, int M){
  constexpr int KP = K + 8;
  __shared__ alignas(16) __hip_bfloat16 At[64][KP];
  __shared__ alignas(16) __hip_bfloat16 Bt[64][KP];
  __shared__ float elp[2][64], erp[2][64];
  const int tid = threadIdx.x;
  const int lane = tid & 63, w = tid >> 6;
  const int mw = w >> 1, nw = w & 1;
  const int m0 = blockIdx.x * 64, by = blockIdx.y, n0 = by * 64;

  if constexpr (!ABF){
    const float* A = (const float*)Av;
    #pragma unroll
    for (int i = 0; i < K/16; i++){
      int q = tid + i*256;
      int row = q / (K/4), c4 = q % (K/4);
      float4 a = make_float4(0.f,0.f,0.f,0.f);
      if (m0 + row < M) a = *(const float4*)&A[(size_t)(m0+row)*K + c4*4];
      *(uint2*)&At[row][c4*4] = make_uint2(packbf(a.x,a.y), packbf(a.z,a.w));
    }
  } else {
    const __hip_bfloat16* A = (const __hip_bfloat16*)Av;
    #pragma unroll
    for (int i = 0; i < K/32; i++){
      int q = tid + i*256;
      int row = q / (K/8), c8 = q % (K/8);
      uint4 u = make_uint4(0,0,0,0);
      if (m0 + row < M) u = *(const uint4*)&A[(size_t)(m0+row)*K + c8*8];
      *(uint4*)&At[row][c8*8] = u;
    }
  }
  #pragma unroll
  for (int i = 0; i < K/16; i++){
    int q = tid + i*256;
    int c = q & 63, k4 = q >> 6;
    float b0 = B[(size_t)(k4*4+0)*ldb + n0 + c];
    float b1 = B[(size_t)(k4*4+1)*ldb + n0 + c];
    float b2 = B[(size_t)(k4*4+2)*ldb + n0 + c];
    float b3 = B[(size_t)(k4*4+3)*ldb + n0 + c];
    *(uint2*)&Bt[c][k4*4] = make_uint2(packbf(b0,b1), packbf(b2,b3));
  }
  __syncthreads();

  f32x4 acc[2][2];
  #pragma unroll
  for (int i = 0; i < 2; i++)
    #pragma unroll
    for (int j = 0; j < 2; j++)
      #pragma unroll
      for (int r = 0; r < 4; r++) acc[i][j][r] = 0.f;

  const int rbase = mw*32, cbase = nw*32;
  const int fr = lane & 15, fg = lane >> 4;
  #pragma unroll
  for (int ks = 0; ks < K/32; ks++){
    short8v a0 = *(const short8v*)&At[rbase + fr     ][ks*32 + fg*8];
    short8v a1 = *(const short8v*)&At[rbase + 16 + fr][ks*32 + fg*8];
    short8v b0 = *(const short8v*)&Bt[cbase + fr     ][ks*32 + fg*8];
    short8v b1 = *(const short8v*)&Bt[cbase + 16 + fr][ks*32 + fg*8];
    acc[0][0] = __builtin_amdgcn_mfma_f32_16x16x32_bf16(a0, b0, acc[0][0], 0,0,0);
    acc[0][1] = __builtin_amdgcn_mfma_f32_16x16x32_bf16(a0, b1, acc[0][1], 0,0,0);
    acc[1][0] = __builtin_amdgcn_mfma_f32_16x16x32_bf16(a1, b0, acc[1][0], 0,0,0);
    acc[1][1] = __builtin_amdgcn_mfma_f32_16x16x32_bf16(a1, b1, acc[1][1], 0,0,0);
  }

  float alv[2], arv[2];
  #pragma unroll
  for (int nt = 0; nt < 2; nt++){
    int col = cbase + nt*16 + fr;
    alv[nt] = al[by*64 + col];
    arv[nt] = ar[by*64 + col];
  }
  #pragma unroll
  for (int mt = 0; mt < 2; mt++){
    #pragma unroll
    for (int r = 0; r < 4; r++){
      float pl = acc[mt][0][r]*alv[0] + acc[mt][1][r]*alv[1];
      float pr = acc[mt][0][r]*arv[0] + acc[mt][1][r]*arv[1];
      #pragma unroll
      for (int o = 1; o < 16; o <<= 1){ pl += __shfl_xor(pl, o); pr += __shfl_xor(pr, o); }
      if (fr == 0){
        int rl = rbase + mt*16 + fg*4 + r;
        elp[nw][rl] = pl; erp[nw][rl] = pr;
      }
    }
  }
  const int NN = H*64;
  #pragma unroll
  for (int mt = 0; mt < 2; mt++){
    #pragma unroll
    for (int r = 0; r < 4; r++){
      int row = m0 + rbase + mt*16 + fg*4 + r;
      if (row < M){
        #pragma unroll
        for (int nt = 0; nt < 2; nt++)
          Cbf[(size_t)row*NN + n0 + cbase + nt*16 + fr] = f2bf(acc[mt][nt][r]);
      }
    }
  }
  __syncthreads();
  if (tid < 64){
    int row = m0 + tid;
    if (row < M){
      el[(size_t)row*H + by] = elp[0][tid] + elp[1][tid];
      er[(size_t)row*H + by] = erp[0][tid] + erp[1][tid];
    }
  }
}

// ---------------- pure gather-aggregate, H=4 (layer 1), grid-stride, 32-bit addr ----------------
__global__ __launch_bounds__(256) void k_gath4(const uint4* __restrict__ fbase, // bf16 [N][256] as uint4[N*32]
      const float* __restrict__ w4, const int* __restrict__ row_start,
      const int* __restrict__ srcp, const float* __restrict__ bias,
      __hip_bfloat16* __restrict__ outb, int N, int nwaves){
  int wv = threadIdx.x >> 6, lane = threadIdx.x & 63;
  int g = lane >> 4, j = lane & 15, h = j >> 2;
  const unsigned jo2 = (unsigned)(j << 1);   // uint4 index within row (2 per lane)

  int n = blockIdx.x*4 + wv;
  if (n >= N) return;
  int rs = row_start[n], re = row_start[n+1];

  while (true){
    int deg = re - rs;
    int nn = n + nwaves;
    int rs_n = 0, re_n = 0;
    if (nn < N){ rs_n = row_start[nn]; re_n = row_start[nn+1]; }  // prefetch next node

    float acc[16];
    #pragma unroll
    for (int k = 0; k < 16; k++) acc[k] = 0.f;
    float Sacc = 0.f;

    int i = 0;
    int full = deg & ~15;          // unguarded 16-edge quads
    for (; i < full; i += 16){
      float wb[4]; uint4 u0[4], u1[4];
      #pragma unroll
      for (int k = 0; k < 4; k++){
        unsigned e = (unsigned)(rs + i + k*4 + g);
        int sb = srcp[e];
        wb[k] = w4[(e << 2) + h];
        unsigned fi = ((unsigned)sb << 5) + jo2;
        u0[k] = fbase[fi];
        u1[k] = fbase[fi + 1];
      }
      #pragma unroll
      for (int k = 0; k < 4; k++){
        float wk = wb[k];
        Sacc += wk;
        acc[0]  += bf_lo(u0[k].x)*wk; acc[1]  += bf_hi(u0[k].x)*wk;
        acc[2]  += bf_lo(u0[k].y)*wk; acc[3]  += bf_hi(u0[k].y)*wk;
        acc[4]  += bf_lo(u0[k].z)*wk; acc[5]  += bf_hi(u0[k].z)*wk;
        acc[6]  += bf_lo(u0[k].w)*wk; acc[7]  += bf_hi(u0[k].w)*wk;
        acc[8]  += bf_lo(u1[k].x)*wk; acc[9]  += bf_hi(u1[k].x)*wk;
        acc[10] += bf_lo(u1[k].y)*wk; acc[11] += bf_hi(u1[k].y)*wk;
        acc[12] += bf_lo(u1[k].z)*wk; acc[13] += bf_hi(u1[k].z)*wk;
        acc[14] += bf_lo(u1[k].w)*wk; acc[15] += bf_hi(u1[k].w)*wk;
      }
    }
    if (i < deg){                  // guarded tail (<=15 edges)
      float wb[4]; uint4 u0[4], u1[4];
      #pragma unroll
      for (int k = 0; k < 4; k++){
        int e = i + k*4 + g;
        wb[k] = 0.f;
        u0[k] = make_uint4(0,0,0,0); u1[k] = make_uint4(0,0,0,0);
        if (e < deg){
          unsigned ee = (unsigned)(rs + e);
          int sb = srcp[ee];
          wb[k] = w4[(ee << 2) + h];
          unsigned fi = ((unsigned)sb << 5) + jo2;
          u0[k] = fbase[fi];
          u1[k] = fbase[fi + 1];
        }
      }
      #pragma unroll
      for (int k = 0; k < 4; k++){
        float wk = wb[k];
        Sacc += wk;
        acc[0]  += bf_lo(u0[k].x)*wk; acc[1]  += bf_hi(u0[k].x)*wk;
        acc[2]  += bf_lo(u0[k].y)*wk; acc[3]  += bf_hi(u0[k].y)*wk;
        acc[4]  += bf_lo(u0[k].z)*wk; acc[5]  += bf_hi(u0[k].z)*wk;
        acc[6]  += bf_lo(u0[k].w)*wk; acc[7]  += bf_hi(u0[k].w)*wk;
        acc[8]  += bf_lo(u1[k].x)*wk; acc[9]  += bf_hi(u1[k].x)*wk;
        acc[10] += bf_lo(u1[k].y)*wk; acc[11] += bf_hi(u1[k].y)*wk;
        acc[12] += bf_lo(u1[k].z)*wk; acc[13] += bf_hi(u1[k].z)*wk;
        acc[14] += bf_lo(u1[k].w)*wk; acc[15] += bf_hi(u1[k].w)*wk;
      }
    }

    #pragma unroll
    for (int k = 0; k < 16; k++){
      acc[k] += __shfl_xor(acc[k], 16);
      acc[k] += __shfl_xor(acc[k], 32);
    }
    Sacc += __shfl_xor(Sacc, 16);
    Sacc += __shfl_xor(Sacc, 32);
    if (g == 0){
      float inv = (deg > 0 && Sacc > 0.f) ? 1.f / Sacc : 0.f;
      float4 b0 = *(const float4*)&bias[j*16 + 0];
      float4 b1 = *(const float4*)&bias[j*16 + 4];
      float4 b2 = *(const float4*)&bias[j*16 + 8];
      float4 b3 = *(const float4*)&bias[j*16 + 12];
      float v[16];
      v[0]=acc[0]*inv+b0.x;  v[1]=acc[1]*inv+b0.y;  v[2]=acc[2]*inv+b0.z;  v[3]=acc[3]*inv+b0.w;
      v[4]=acc[4]*inv+b1.x;  v[5]=acc[5]*inv+b1.y;  v[6]=acc[6]*inv+b1.z;  v[7]=acc[7]*inv+b1.w;
      v[8]=acc[8]*inv+b2.x;  v[9]=acc[9]*inv+b2.y;  v[10]=acc[10]*inv+b2.z; v[11]=acc[11]*inv+b2.w;
      v[12]=acc[12]*inv+b3.x; v[13]=acc[13]*inv+b3.y; v[14]=acc[14]*inv+b3.z; v[15]=acc[15]*inv+b3.w;
      #pragma unroll
      for (int k = 0; k < 16; k++) v[k] = fmaxf(v[k], 0.f);   // relu (layer 1)
      uint4 o0, o1;
      o0.x = packbf(v[0], v[1]);   o0.y = packbf(v[2], v[3]);
      o0.z = packbf(v[4], v[5]);   o0.w = packbf(v[6], v[7]);
      o1.x = packbf(v[8], v[9]);   o1.y = packbf(v[10], v[11]);
      o1.z = packbf(v[12], v[13]); o1.w = packbf(v[14], v[15]);
      uint4* op = (uint4*)outb + (size_t)n*32 + (j << 1);
      op[0] = o0; op[1] = o1;
    }

    if (nn >= N) break;
    n = nn; rs = rs_n; re = re_n;
  }
}

// ---------------- gather-aggregate, H=1 (layer 2), inline weights, fp32 out ----------------
__global__ __launch_bounds__(256) void k_gath1(const uint2* __restrict__ fbase, // bf16 [N][64] as uint2[N*16]
      const float* __restrict__ el2, const float* __restrict__ er2,
      const int* __restrict__ row_start, const int* __restrict__ srcp,
      const float* __restrict__ bias, float* __restrict__ out, int N, int nwaves){
  int wv = threadIdx.x >> 6, lane = threadIdx.x & 63;
  int g = lane >> 4, j = lane & 15;
  const unsigned jo = (unsigned)j;

  int n = blockIdx.x*4 + wv;
  if (n >= N) return;
  int rs = row_start[n], re = row_start[n+1];

  while (true){
    int deg = re - rs;
    int nn = n + nwaves;
    int rs_n = 0, re_n = 0;
    if (nn < N){ rs_n = row_start[nn]; re_n = row_start[nn+1]; }

    float ern = er2[n];
    float acc[4] = {0.f, 0.f, 0.f, 0.f};
    float Sacc = 0.f;

    int i = 0;
    int full = deg & ~15;
    for (; i < full; i += 16){
      float wb[4]; uint2 u[4];
      #pragma unroll
      for (int k = 0; k < 4; k++){
        unsigned e = (unsigned)(rs + i + k*4 + g);
        int sb = srcp[e];                       // broadcast within 16-lane group
        float x = el2[sb] + ern;                // broadcast
        x = x > 0.f ? x : 0.2f*x;
        wb[k] = __expf(x);
        u[k] = fbase[((unsigned)sb << 4) + jo];
      }
      #pragma unroll
      for (int k = 0; k < 4; k++){
        float wk = wb[k];
        Sacc += wk;
        acc[0] += bf_lo(u[k].x)*wk; acc[1] += bf_hi(u[k].x)*wk;
        acc[2] += bf_lo(u[k].y)*wk; acc[3] += bf_hi(u[k].y)*wk;
      }
    }
    if (i < deg){
      float wb[4]; uint2 u[4];
      #pragma unroll
      for (int k = 0; k < 4; k++){
        int e = i + k*4 + g;
        wb[k] = 0.f;
        u[k] = make_uint2(0,0);
        if (e < deg){
          unsigned ee = (unsigned)(rs + e);
          int sb = srcp[ee];
          float x = el2[sb] + ern;
          x = x > 0.f ? x : 0.2f*x;
          wb[k] = __expf(x);
          u[k] = fbase[((unsigned)sb << 4) + jo];
        }
      }
      #pragma unroll
      for (int k = 0; k < 4; k++){
        float wk = wb[k];
        Sacc += wk;
        acc[0] += bf_lo(u[k].x)*wk; acc[1] += bf_hi(u[k].x)*wk;
        acc[2] += bf_lo(u[k].y)*wk; acc[3] += bf_hi(u[k].y)*wk;
      }
    }

    #pragma unroll
    for (int k = 0; k < 4; k++){
      acc[k] += __shfl_xor(acc[k], 16);
      acc[k] += __shfl_xor(acc[k], 32);
    }
    Sacc += __shfl_xor(Sacc, 16);
    Sacc += __shfl_xor(Sacc, 32);
    if (g == 0){
      float inv = (deg > 0 && Sacc > 0.f) ? 1.f / Sacc : 0.f;
      float4 b = *(const float4*)&bias[j*4];
      float4 o;
      o.x = acc[0]*inv + b.x; o.y = acc[1]*inv + b.y;
      o.z = acc[2]*inv + b.z; o.w = acc[3]*inv + b.w;
      *(float4*)&out[(size_t)n*64 + j*4] = o;
    }

    if (nn >= N) break;
    n = nn; rs = rs_n; re = re_n;
  }
}

// ---------------- launch ----------------
extern "C" void kernel_launch(void* const* d_in, const int* in_sizes, int n_in,
                              void* d_out, int out_size, void* d_ws, size_t ws_size,
                              hipStream_t stream) {
  const float* emb = (const float*)d_in[0];
  const int*   src = (const int*)d_in[1];
  const int*   dst = (const int*)d_in[2];
  const float* W1  = (const float*)d_in[3];
  const float* al1 = (const float*)d_in[4];
  const float* ar1 = (const float*)d_in[5];
  const float* b1  = (const float*)d_in[6];
  const float* W2  = (const float*)d_in[7];
  const float* al2 = (const float*)d_in[8];
  const float* ar2 = (const float*)d_in[9];
  const float* b2  = (const float*)d_in[10];
  float* out = (float*)d_out;

  const int N = in_sizes[0] / 128;
  const int E = in_sizes[1];

  char* p = (char*)d_ws;
  auto alloc = [&](size_t bytes) -> void* {
    void* r = (void*)p; p += (bytes + 255) & ~(size_t)255; return r;
  };
  __hip_bfloat16* feat1b = (__hip_bfloat16*)alloc((size_t)N*256*2);
  __hip_bfloat16* h1b    = (__hip_bfloat16*)alloc((size_t)N*256*2);
  __hip_bfloat16* feat2b = (__hip_bfloat16*)alloc((size_t)N*64*2);
  float* el1             = (float*)alloc((size_t)N*4*4);
  float* er1             = (float*)alloc((size_t)N*4*4);
  float* el2             = (float*)alloc((size_t)N*4);
  float* er2             = (float*)alloc((size_t)N*4);
  int*   deg             = (int*)alloc((size_t)N*4);
  int*   row_start       = (int*)alloc((size_t)(N+1)*4);
  int*   cursor          = (int*)alloc((size_t)N*4);
  int*   blocksum        = (int*)alloc((size_t)DIV_UP(N,1024)*4);
  int*   srcp            = (int*)alloc((size_t)E*4);
  float* w4              = (float*)alloc((size_t)E*16);

  const int nb = DIV_UP(N, 1024);
  const int gblocks = min(DIV_UP(N, 4), 2048);
  const int nwaves  = gblocks * 4;
  const int gemmBlocks = DIV_UP(N, 64);
  const int cntBlocks  = DIV_UP(E, 256);

  hipMemsetAsync(deg, 0, (size_t)N*4, stream);

  // GEMM1 (layer-1 features + el1/er1) fused with degree count (independent work)
  k_gemm1_count<<<gemmBlocks + cntBlocks, 256, 0, stream>>>(
      emb, W1, (unsigned short*)feat1b, al1, ar1, el1, er1, N,
      dst, deg, E, gemmBlocks);

  k_scan1<<<nb, 256, 0, stream>>>(deg, blocksum, N);
  k_scan3<<<nb, 256, 0, stream>>>(deg, blocksum, nb, row_start, cursor, N);
  k_fillw4<<<DIV_UP(E,256), 256, 0, stream>>>(dst, src, cursor, srcp,
      (const float4*)el1, (const float4*)er1, (float4*)w4, E);

  k_gath4<<<gblocks, 256, 0, stream>>>((const uint4*)feat1b, w4, row_start,
                                       srcp, b1, h1b, N, nwaves);
  // Layer 2
  k_gemm_mfma<256,1,true><<<dim3(DIV_UP(N,64), 1), 256, 0, stream>>>(
      h1b, W2, 64, (unsigned short*)feat2b, al2, ar2, el2, er2, N);
  k_gath1<<<gblocks, 256, 0, stream>>>((const uint2*)feat2b, el2, er2,
                                       row_start, srcp, b2, out, N, nwaves);
}